// Round 2
// baseline (711.824 us; speedup 1.0000x reference)
//
#include <hip/hip_runtime.h>

// Problem dims (fixed by reference setup_inputs)
#define TT 512
#define BB 8
#define HH 512
#define VV 32000
#define RR (TT * BB)   // 4096 rows (t,b)

#define SCAN_BLOCKS  8          // blocks 0..7: one per batch lane b
#define BCAST_ROWS   8          // rows per broadcast block (1 MB contiguous)
#define BCAST_BLOCKS (RR / BCAST_ROWS)   // 512

__device__ __forceinline__ float clip01(float x) { return fminf(fmaxf(x, 0.0f), 1.0f); }

// ---------------------------------------------------------------------------
// Fused kernel. blockIdx < 8  : the 3-layer LIF scan (body UNCHANGED from the
//                               verified round-1 kernel; one block per b).
//       blockIdx 8..519       : out[r][:] = bout broadcast, 8 consecutive
//                               rows (1 MB) per block, plain float4 stores.
// The broadcast is speculative: rows that turn out to have layer-3 spikes are
// rewritten densely by fixup_kernel (next dispatch, same stream => ordered).
// This removes the in-stream serialization scan -> 524MB write: the write now
// runs on the 248 CUs the 8-block scan leaves idle.
// ---------------------------------------------------------------------------
__global__ void __launch_bounds__(512) scan_bcast_kernel(
        const int* __restrict__ x, const float* __restrict__ emb,
        const float* __restrict__ pos,
        const float* __restrict__ beta1, const float* __restrict__ beta2,
        const float* __restrict__ beta3,
        const float* __restrict__ W2, const float* __restrict__ b2,
        const float* __restrict__ W3, const float* __restrict__ b3,
        int* __restrict__ act1, int* __restrict__ act2, int* __restrict__ act3,
        int* __restrict__ cnt3_g,
        const float* __restrict__ bout, float* __restrict__ out) {

    if (blockIdx.x >= SCAN_BLOCKS) {
        // ---- broadcast path: out rows = bout ----
        const int tid = threadIdx.x;
        const int v0 = tid * 4;
        float4 bv[16];
#pragma unroll
        for (int k = 0; k < 16; ++k) {
            int v = v0 + k * 2048;
            if (v < VV) bv[k] = *(const float4*)(bout + v);
        }
        const int r0 = (blockIdx.x - SCAN_BLOCKS) * BCAST_ROWS;
#pragma unroll
        for (int rr = 0; rr < BCAST_ROWS; ++rr) {
            float* __restrict__ orow = out + (size_t)(r0 + rr) * VV;
#pragma unroll
            for (int k = 0; k < 16; ++k) {
                int v = v0 + k * 2048;
                if (v < VV) *(float4*)(orow + v) = bv[k];
            }
        }
        return;
    }

    // ---- scan path (byte-identical logic to the verified round-1 kernel) ----
    __shared__ int x_lds[TT];
    __shared__ int c1[TT], c2[TT], c3[TT];
    const int b = blockIdx.x;    // 0..7
    const int h = threadIdx.x;   // 0..511 (doubles as t-index for preloads)

    x_lds[h] = x[h * BB + b];    // x is [T,B]; t == threadIdx here
    c1[h] = 0; c2[h] = 0; c3[h] = 0;
    __syncthreads();

    // ---- phase 1: embedding-driven LIF ----
    {
        float bt = clip01(beta1[h]);
        float m = 0.0f;
        for (int t0 = 0; t0 < TT; t0 += 32) {
            float ev[32], pv[32];
#pragma unroll
            for (int u = 0; u < 32; ++u) {
                int xv = x_lds[t0 + u];
                ev[u] = emb[((size_t)xv << 9) + h];
                pv[u] = pos[((t0 + u) << 9) + h];
            }
#pragma unroll
            for (int u = 0; u < 32; ++u) {
                float inp = ev[u] + pv[u];
                // reset = spike(m_prev-1); m = beta*m_prev + inp - reset; spk = spike(m-1)
                float reset = (m > 1.0f) ? 1.0f : 0.0f;  // (m-1>0) == (m>1) exactly in fp32
                m = bt * m + inp - reset;
                if (m > 1.0f) {
                    int t = t0 + u;
                    int p = atomicAdd(&c1[t], 1);
                    act1[((t * BB + b) << 9) + p] = h;
                }
            }
        }
    }
    __syncthreads();   // publish c1 (LDS) + act1 (global, same-CU L1) to the block

    // ---- phase 2: hidden layer 2 (fused sparse matmul + LIF) ----
    {
        float bh = b2[h];
        float inp0 = fmaxf(bh, 0.0f);
        float bt = clip01(beta2[h]);
        float m = 0.0f;
        for (int t0 = 0; t0 < TT; t0 += 16) {
            int n[16];
#pragma unroll
            for (int u = 0; u < 16; ++u) n[u] = c1[t0 + u];
#pragma unroll
            for (int u = 0; u < 16; ++u) {
                float inp;
                if (n[u] == 0) {
                    inp = inp0;
                } else {
                    float acc = bh;
                    const int* a = act1 + (((t0 + u) * BB + b) << 9);
                    for (int i = 0; i < n[u]; ++i) acc += W2[(h << 9) + a[i]];
                    inp = fmaxf(acc, 0.0f);
                }
                float reset = (m > 1.0f) ? 1.0f : 0.0f;
                m = bt * m + inp - reset;
                if (m > 1.0f) {
                    int t = t0 + u;
                    int p = atomicAdd(&c2[t], 1);
                    act2[((t * BB + b) << 9) + p] = h;
                }
            }
        }
    }
    __syncthreads();

    // ---- phase 3: hidden layer 3 ----
    {
        float bh = b3[h];
        float inp0 = fmaxf(bh, 0.0f);
        float bt = clip01(beta3[h]);
        float m = 0.0f;
        for (int t0 = 0; t0 < TT; t0 += 16) {
            int n[16];
#pragma unroll
            for (int u = 0; u < 16; ++u) n[u] = c2[t0 + u];
#pragma unroll
            for (int u = 0; u < 16; ++u) {
                float inp;
                if (n[u] == 0) {
                    inp = inp0;
                } else {
                    float acc = bh;
                    const int* a = act2 + (((t0 + u) * BB + b) << 9);
                    for (int i = 0; i < n[u]; ++i) acc += W3[(h << 9) + a[i]];
                    inp = fmaxf(acc, 0.0f);
                }
                float reset = (m > 1.0f) ? 1.0f : 0.0f;
                m = bt * m + inp - reset;
                if (m > 1.0f) {
                    int t = t0 + u;
                    int p = atomicAdd(&c3[t], 1);
                    act3[((t * BB + b) << 9) + p] = h;
                }
            }
        }
    }
    __syncthreads();
    cnt3_g[h * BB + b] = c3[h];   // h doubles as t; export layer-3 counts
}

// ---------------------------------------------------------------------------
// Fixup: rows whose layer-3 spike count is nonzero get densely recomputed
// out[r][v] = bout[v] + sum_{k in act3[r]} Wout[v][k], overwriting the
// speculative broadcast. For the benchmark input all counts are 0, so every
// block reads 8 ints and exits (~3 us total). Correct for arbitrary inputs.
// ---------------------------------------------------------------------------
__global__ void __launch_bounds__(512) fixup_kernel(
        const int* __restrict__ cnt, const int* __restrict__ act,
        const float* __restrict__ Wout, const float* __restrict__ bout,
        float* __restrict__ out) {
    __shared__ int ns[BCAST_ROWS];
    const int r0 = blockIdx.x * BCAST_ROWS;
    if (threadIdx.x < BCAST_ROWS) ns[threadIdx.x] = cnt[r0 + threadIdx.x];
    __syncthreads();
    int any = 0;
#pragma unroll
    for (int i = 0; i < BCAST_ROWS; ++i) any |= ns[i];
    if (any == 0) return;   // fast path: broadcast already correct

    const int tid = threadIdx.x;
    const int v0 = tid * 4;
    for (int rr = 0; rr < BCAST_ROWS; ++rr) {
        const int n = ns[rr];
        if (n == 0) continue;
        const int r = r0 + rr;
        const int* __restrict__ a = act + (r << 9);
        float* __restrict__ orow = out + (size_t)r * VV;
#pragma unroll
        for (int k = 0; k < 16; ++k) {
            int v = v0 + k * 2048;
            if (v < VV) {
                float4 acc = *(const float4*)(bout + v);
                for (int i = 0; i < n; ++i) {
                    int kk = a[i];
                    acc.x += Wout[(size_t)(v + 0) * HH + kk];
                    acc.y += Wout[(size_t)(v + 1) * HH + kk];
                    acc.z += Wout[(size_t)(v + 2) * HH + kk];
                    acc.w += Wout[(size_t)(v + 3) * HH + kk];
                }
                *(float4*)(orow + v) = acc;
            }
        }
    }
}

extern "C" void kernel_launch(void* const* d_in, const int* in_sizes, int n_in,
                              void* d_out, int out_size, void* d_ws, size_t ws_size,
                              hipStream_t stream) {
    const int*   x     = (const int*)d_in[0];
    const float* emb   = (const float*)d_in[1];
    const float* pos   = (const float*)d_in[2];
    const float* beta1 = (const float*)d_in[3];
    const float* beta2 = (const float*)d_in[4];
    const float* beta3 = (const float*)d_in[5];
    const float* W2    = (const float*)d_in[6];
    const float* b2    = (const float*)d_in[7];
    const float* W3    = (const float*)d_in[8];
    const float* b3    = (const float*)d_in[9];
    const float* Wout  = (const float*)d_in[10];
    const float* bout  = (const float*)d_in[11];
    float* out = (float*)d_out;

    // ws layout: act1 | act2 | act3 (R*H i32 each) | cnt3 (R i32)
    int* act1 = (int*)d_ws;
    int* act2 = act1 + (size_t)RR * HH;
    int* act3 = act2 + (size_t)RR * HH;
    int* cnt3 = act3 + (size_t)RR * HH;

    scan_bcast_kernel<<<SCAN_BLOCKS + BCAST_BLOCKS, HH, 0, stream>>>(
        x, emb, pos, beta1, beta2, beta3, W2, b2, W3, b3,
        act1, act2, act3, cnt3, bout, out);
    fixup_kernel<<<BCAST_BLOCKS, HH, 0, stream>>>(cnt3, act3, Wout, bout, out);
}

// Round 3
// 688.879 us; speedup vs baseline: 1.0333x; 1.0333x over previous
//
#include <hip/hip_runtime.h>

// Problem dims (fixed by reference setup_inputs)
#define TT 512
#define BB 8
#define HH 512
#define VV 32000
#define RR (TT * BB)   // 4096 rows (t,b)

typedef float v4f __attribute__((ext_vector_type(4)));

__device__ __forceinline__ float clip01(float x) { return fminf(fmaxf(x, 0.0f), 1.0f); }

// ---------------------------------------------------------------------------
// Mega-kernel: all three LIF layers fused. 8 blocks (one per batch lane b),
// 512 threads (one per hidden unit h). Phases separated by __syncthreads();
// spike counts in LDS, spike index lists in global (read back only on the
// rare nonzero path). UNCHANGED from the verified round-1 kernel.
// ---------------------------------------------------------------------------
__global__ void __launch_bounds__(512) snn_scan_kernel(
        const int* __restrict__ x, const float* __restrict__ emb,
        const float* __restrict__ pos,
        const float* __restrict__ beta1, const float* __restrict__ beta2,
        const float* __restrict__ beta3,
        const float* __restrict__ W2, const float* __restrict__ b2,
        const float* __restrict__ W3, const float* __restrict__ b3,
        int* __restrict__ act1, int* __restrict__ act2, int* __restrict__ act3,
        int* __restrict__ cnt3_g) {
    __shared__ int x_lds[TT];
    __shared__ int c1[TT], c2[TT], c3[TT];
    const int b = blockIdx.x;    // 0..7
    const int h = threadIdx.x;   // 0..511 (doubles as t-index for preloads)

    x_lds[h] = x[h * BB + b];    // x is [T,B]; t == threadIdx here
    c1[h] = 0; c2[h] = 0; c3[h] = 0;
    __syncthreads();

    // ---- phase 1: embedding-driven LIF ----
    {
        float bt = clip01(beta1[h]);
        float m = 0.0f;
        for (int t0 = 0; t0 < TT; t0 += 32) {
            float ev[32], pv[32];
#pragma unroll
            for (int u = 0; u < 32; ++u) {
                int xv = x_lds[t0 + u];
                ev[u] = emb[((size_t)xv << 9) + h];
                pv[u] = pos[((t0 + u) << 9) + h];
            }
#pragma unroll
            for (int u = 0; u < 32; ++u) {
                float inp = ev[u] + pv[u];
                // reset = spike(m_prev-1); m = beta*m_prev + inp - reset; spk = spike(m-1)
                float reset = (m > 1.0f) ? 1.0f : 0.0f;  // (m-1>0) == (m>1) exactly in fp32
                m = bt * m + inp - reset;
                if (m > 1.0f) {
                    int t = t0 + u;
                    int p = atomicAdd(&c1[t], 1);
                    act1[((t * BB + b) << 9) + p] = h;
                }
            }
        }
    }
    __syncthreads();   // publish c1 (LDS) + act1 (global, same-CU L1) to the block

    // ---- phase 2: hidden layer 2 (fused sparse matmul + LIF) ----
    {
        float bh = b2[h];
        float inp0 = fmaxf(bh, 0.0f);
        float bt = clip01(beta2[h]);
        float m = 0.0f;
        for (int t0 = 0; t0 < TT; t0 += 16) {
            int n[16];
#pragma unroll
            for (int u = 0; u < 16; ++u) n[u] = c1[t0 + u];
#pragma unroll
            for (int u = 0; u < 16; ++u) {
                float inp;
                if (n[u] == 0) {
                    inp = inp0;
                } else {
                    float acc = bh;
                    const int* a = act1 + (((t0 + u) * BB + b) << 9);
                    for (int i = 0; i < n[u]; ++i) acc += W2[(h << 9) + a[i]];
                    inp = fmaxf(acc, 0.0f);
                }
                float reset = (m > 1.0f) ? 1.0f : 0.0f;
                m = bt * m + inp - reset;
                if (m > 1.0f) {
                    int t = t0 + u;
                    int p = atomicAdd(&c2[t], 1);
                    act2[((t * BB + b) << 9) + p] = h;
                }
            }
        }
    }
    __syncthreads();

    // ---- phase 3: hidden layer 3 ----
    {
        float bh = b3[h];
        float inp0 = fmaxf(bh, 0.0f);
        float bt = clip01(beta3[h]);
        float m = 0.0f;
        for (int t0 = 0; t0 < TT; t0 += 16) {
            int n[16];
#pragma unroll
            for (int u = 0; u < 16; ++u) n[u] = c2[t0 + u];
#pragma unroll
            for (int u = 0; u < 16; ++u) {
                float inp;
                if (n[u] == 0) {
                    inp = inp0;
                } else {
                    float acc = bh;
                    const int* a = act2 + (((t0 + u) * BB + b) << 9);
                    for (int i = 0; i < n[u]; ++i) acc += W3[(h << 9) + a[i]];
                    inp = fmaxf(acc, 0.0f);
                }
                float reset = (m > 1.0f) ? 1.0f : 0.0f;
                m = bt * m + inp - reset;
                if (m > 1.0f) {
                    int t = t0 + u;
                    int p = atomicAdd(&c3[t], 1);
                    act3[((t * BB + b) << 9) + p] = h;
                }
            }
        }
    }
    __syncthreads();
    cnt3_g[h * BB + b] = c3[h];   // h doubles as t; export layer-3 counts
}

// ---------------------------------------------------------------------------
// Output GEMM: out[r][v] = bout[v] + sum_{k in act3[r]} Wout[v][k].
// Round-1 structure (8 consecutive rows = 1 MB contiguous per block, bout
// preloaded once into registers), with ONE change: nontemporal stores.
// Single-variable probe: if plain cached stores were paying L2
// write-allocate (RFO), NT bypass removes 524 MB of hidden fetch traffic.
// Output is never re-read, so NT is semantically ideal.
// ---------------------------------------------------------------------------
#define ROWS_PER_BLK 8

__global__ void __launch_bounds__(512) out_gemm_kernel(
        const int* __restrict__ cnt, const int* __restrict__ act,
        const float* __restrict__ Wout, const float* __restrict__ bout,
        float* __restrict__ out) {
    const int tid = threadIdx.x;
    const int v0 = tid * 4;

    // preload bout: 16 strided float4 per thread covers 32768 >= 32000 slots
    float4 bv[16];
#pragma unroll
    for (int k = 0; k < 16; ++k) {
        int v = v0 + k * 2048;
        if (v < VV) bv[k] = *(const float4*)(bout + v);
    }

    const int r0 = blockIdx.x * ROWS_PER_BLK;
#pragma unroll
    for (int rr = 0; rr < ROWS_PER_BLK; ++rr) {
        const int r = r0 + rr;
        const int n = cnt[r];
        float* __restrict__ orow = out + (size_t)r * VV;
        if (n == 0) {
            // pure broadcast of bout from registers, streaming NT stores
#pragma unroll
            for (int k = 0; k < 16; ++k) {
                int v = v0 + k * 2048;
                if (v < VV) {
                    v4f st = {bv[k].x, bv[k].y, bv[k].z, bv[k].w};
                    __builtin_nontemporal_store(st, (v4f*)(orow + v));
                }
            }
        } else {
            const int* __restrict__ a = act + (r << 9);
#pragma unroll
            for (int k = 0; k < 16; ++k) {
                int v = v0 + k * 2048;
                if (v < VV) {
                    float4 acc = bv[k];
                    for (int i = 0; i < n; ++i) {
                        int kk = a[i];
                        acc.x += Wout[(size_t)(v + 0) * HH + kk];
                        acc.y += Wout[(size_t)(v + 1) * HH + kk];
                        acc.z += Wout[(size_t)(v + 2) * HH + kk];
                        acc.w += Wout[(size_t)(v + 3) * HH + kk];
                    }
                    v4f st = {acc.x, acc.y, acc.z, acc.w};
                    __builtin_nontemporal_store(st, (v4f*)(orow + v));
                }
            }
        }
    }
}

extern "C" void kernel_launch(void* const* d_in, const int* in_sizes, int n_in,
                              void* d_out, int out_size, void* d_ws, size_t ws_size,
                              hipStream_t stream) {
    const int*   x     = (const int*)d_in[0];
    const float* emb   = (const float*)d_in[1];
    const float* pos   = (const float*)d_in[2];
    const float* beta1 = (const float*)d_in[3];
    const float* beta2 = (const float*)d_in[4];
    const float* beta3 = (const float*)d_in[5];
    const float* W2    = (const float*)d_in[6];
    const float* b2    = (const float*)d_in[7];
    const float* W3    = (const float*)d_in[8];
    const float* b3    = (const float*)d_in[9];
    const float* Wout  = (const float*)d_in[10];
    const float* bout  = (const float*)d_in[11];
    float* out = (float*)d_out;

    // ws layout: act1 | act2 | act3 (R*H i32 each) | cnt3 (R i32)
    int* act1 = (int*)d_ws;
    int* act2 = act1 + (size_t)RR * HH;
    int* act3 = act2 + (size_t)RR * HH;
    int* cnt3 = act3 + (size_t)RR * HH;

    snn_scan_kernel<<<BB, HH, 0, stream>>>(x, emb, pos, beta1, beta2, beta3,
                                           W2, b2, W3, b3, act1, act2, act3, cnt3);
    out_gemm_kernel<<<RR / ROWS_PER_BLK, HH, 0, stream>>>(cnt3, act3, Wout, bout, out);
}

// Round 4
// 688.396 us; speedup vs baseline: 1.0340x; 1.0007x over previous
//
#include <hip/hip_runtime.h>

// Problem dims (fixed by reference setup_inputs)
#define TT 512
#define BB 8
#define HH 512
#define VV 32000
#define RR (TT * BB)   // 4096 rows (t,b)
#define HC 8           // h-chunks per batch lane
#define CHUNK (HH / HC) // 64 hidden units per block

typedef float v4f __attribute__((ext_vector_type(4)));

__device__ __forceinline__ float clip01(float x) { return fminf(fmaxf(x, 0.0f), 1.0f); }

// ---------------------------------------------------------------------------
// DECISIVE PROBE: scan split into 3 per-layer kernels on 64 blocks (8 b x 8
// h-chunks, 64 threads each) instead of one 8-block kernel. If the old scan
// was MSHR-throttled (8 CUs x 512 outstanding wave-loads each), spreading the
// gather over 64 CUs' miss-handling capacity is a big win; if the scan was
// already ~25 us, this is neutral (+3 dispatch gaps). Spike counts move from
// LDS to global atomics (pre-zeroed via hipMemsetAsync); kernel boundaries
// provide the cross-block layer sync, so arbitrary-input correctness holds.
// b = blockIdx&7 => all h-chunks of one batch lane land on one XCD (emb rows
// for that lane become L2-local).
// ---------------------------------------------------------------------------
__global__ void __launch_bounds__(64) lif1_kernel(
        const int* __restrict__ x, const float* __restrict__ emb,
        const float* __restrict__ pos, const float* __restrict__ beta1,
        int* __restrict__ act1, int* __restrict__ cnt1) {
    __shared__ int x_lds[TT];
    const int b  = blockIdx.x & 7;
    const int hc = blockIdx.x >> 3;
    const int tid = threadIdx.x;
    for (int i = tid; i < TT; i += 64) x_lds[i] = x[i * BB + b];
    __syncthreads();

    const int h = hc * CHUNK + tid;
    const float bt = clip01(beta1[h]);
    float m = 0.0f;
    for (int t0 = 0; t0 < TT; t0 += 32) {
        float ev[32], pv[32];
#pragma unroll
        for (int u = 0; u < 32; ++u) {
            int xv = x_lds[t0 + u];
            ev[u] = emb[((size_t)xv << 9) + h];
            pv[u] = pos[((t0 + u) << 9) + h];
        }
#pragma unroll
        for (int u = 0; u < 32; ++u) {
            float inp = ev[u] + pv[u];
            // reset = spike(m_prev-1); m = beta*m_prev + inp - reset; spk = spike(m-1)
            float reset = (m > 1.0f) ? 1.0f : 0.0f;  // (m-1>0) == (m>1) exactly in fp32
            m = bt * m + inp - reset;
            if (m > 1.0f) {
                int t = t0 + u;
                int p = atomicAdd(&cnt1[t * BB + b], 1);   // device-scope, cross-block safe
                act1[((t * BB + b) << 9) + p] = h;
            }
        }
    }
}

// Hidden layer (2 or 3): inp = relu(bvec + sum_{k in act_in[t,b]} W[h][k])
__global__ void __launch_bounds__(64) lifh_kernel(
        const float* __restrict__ W, const float* __restrict__ bvec,
        const float* __restrict__ beta,
        const int* __restrict__ cnt_in, const int* __restrict__ act_in,
        int* __restrict__ act_out, int* __restrict__ cnt_out) {
    __shared__ int c_lds[TT];
    const int b  = blockIdx.x & 7;
    const int hc = blockIdx.x >> 3;
    const int tid = threadIdx.x;
    for (int i = tid; i < TT; i += 64) c_lds[i] = cnt_in[i * BB + b];
    __syncthreads();

    const int h = hc * CHUNK + tid;
    const float bh = bvec[h];
    const float inp0 = fmaxf(bh, 0.0f);
    const float bt = clip01(beta[h]);
    float m = 0.0f;
    for (int t0 = 0; t0 < TT; t0 += 16) {
        int n[16];
#pragma unroll
        for (int u = 0; u < 16; ++u) n[u] = c_lds[t0 + u];
#pragma unroll
        for (int u = 0; u < 16; ++u) {
            float inp;
            if (n[u] == 0) {
                inp = inp0;
            } else {
                float acc = bh;
                const int* a = act_in + (((t0 + u) * BB + b) << 9);
                for (int i = 0; i < n[u]; ++i) acc += W[(h << 9) + a[i]];
                inp = fmaxf(acc, 0.0f);
            }
            float reset = (m > 1.0f) ? 1.0f : 0.0f;
            m = bt * m + inp - reset;
            if (m > 1.0f) {
                int t = t0 + u;
                int p = atomicAdd(&cnt_out[t * BB + b], 1);
                act_out[((t * BB + b) << 9) + p] = h;
            }
        }
    }
}

// ---------------------------------------------------------------------------
// Output GEMM (round-3 verified version, unchanged): out[r][v] = bout[v] +
// sum_{k in act3[r]} Wout[v][k]. 8 consecutive rows (1 MB contiguous) per
// block, bout preloaded to registers, NT float4 streaming stores. All store
// variants measured equal => this is at the 524 MB write floor.
// ---------------------------------------------------------------------------
#define ROWS_PER_BLK 8

__global__ void __launch_bounds__(512) out_gemm_kernel(
        const int* __restrict__ cnt, const int* __restrict__ act,
        const float* __restrict__ Wout, const float* __restrict__ bout,
        float* __restrict__ out) {
    const int tid = threadIdx.x;
    const int v0 = tid * 4;

    float4 bv[16];
#pragma unroll
    for (int k = 0; k < 16; ++k) {
        int v = v0 + k * 2048;
        if (v < VV) bv[k] = *(const float4*)(bout + v);
    }

    const int r0 = blockIdx.x * ROWS_PER_BLK;
#pragma unroll
    for (int rr = 0; rr < ROWS_PER_BLK; ++rr) {
        const int r = r0 + rr;
        const int n = cnt[r];
        float* __restrict__ orow = out + (size_t)r * VV;
        if (n == 0) {
#pragma unroll
            for (int k = 0; k < 16; ++k) {
                int v = v0 + k * 2048;
                if (v < VV) {
                    v4f st = {bv[k].x, bv[k].y, bv[k].z, bv[k].w};
                    __builtin_nontemporal_store(st, (v4f*)(orow + v));
                }
            }
        } else {
            const int* __restrict__ a = act + (r << 9);
#pragma unroll
            for (int k = 0; k < 16; ++k) {
                int v = v0 + k * 2048;
                if (v < VV) {
                    float4 acc = bv[k];
                    for (int i = 0; i < n; ++i) {
                        int kk = a[i];
                        acc.x += Wout[(size_t)(v + 0) * HH + kk];
                        acc.y += Wout[(size_t)(v + 1) * HH + kk];
                        acc.z += Wout[(size_t)(v + 2) * HH + kk];
                        acc.w += Wout[(size_t)(v + 3) * HH + kk];
                    }
                    v4f st = {acc.x, acc.y, acc.z, acc.w};
                    __builtin_nontemporal_store(st, (v4f*)(orow + v));
                }
            }
        }
    }
}

extern "C" void kernel_launch(void* const* d_in, const int* in_sizes, int n_in,
                              void* d_out, int out_size, void* d_ws, size_t ws_size,
                              hipStream_t stream) {
    const int*   x     = (const int*)d_in[0];
    const float* emb   = (const float*)d_in[1];
    const float* pos   = (const float*)d_in[2];
    const float* beta1 = (const float*)d_in[3];
    const float* beta2 = (const float*)d_in[4];
    const float* beta3 = (const float*)d_in[5];
    const float* W2    = (const float*)d_in[6];
    const float* b2    = (const float*)d_in[7];
    const float* W3    = (const float*)d_in[8];
    const float* b3    = (const float*)d_in[9];
    const float* Wout  = (const float*)d_in[10];
    const float* bout  = (const float*)d_in[11];
    float* out = (float*)d_out;

    // ws layout: act1 | act2 | act3 (R*H i32 each) | cnt1 | cnt2 | cnt3 (R i32 each, contiguous)
    int* act1 = (int*)d_ws;
    int* act2 = act1 + (size_t)RR * HH;
    int* act3 = act2 + (size_t)RR * HH;
    int* cnt1 = act3 + (size_t)RR * HH;
    int* cnt2 = cnt1 + RR;
    int* cnt3 = cnt2 + RR;

    // zero the three spike-count arrays (48 KB) — required for global atomics
    hipMemsetAsync(cnt1, 0, 3 * RR * sizeof(int), stream);

    lif1_kernel<<<BB * HC, CHUNK, 0, stream>>>(x, emb, pos, beta1, act1, cnt1);
    lifh_kernel<<<BB * HC, CHUNK, 0, stream>>>(W2, b2, beta2, cnt1, act1, act2, cnt2);
    lifh_kernel<<<BB * HC, CHUNK, 0, stream>>>(W3, b3, beta3, cnt2, act2, act3, cnt3);
    out_gemm_kernel<<<RR / ROWS_PER_BLK, HH, 0, stream>>>(cnt3, act3, Wout, bout, out);
}